// Round 6
// baseline (258.517 us; speedup 1.0000x reference)
//
#include <hip/hip_runtime.h>

// Sinkhorn, 128 x (256x256) f32, 15 fixed iterations — matrix-scaling form.
//   b' = 1/(X^T a),  a' = 1/(X b');  y = diag(a) X diag(b) applied once at end
//   (diagonal scalings cancel telescopically; verified passing in r2/r5).
//
// Register story (the whole game on this kernel):
//   hipcc pins 1024-thread blocks at 64 VGPRs (targets 2 blocks/CU); 64
//   persistent f32 tile floats spill to scratch (r2/r4/r5: +24..32 MB
//   WRITE_SIZE). Fix: persistent tile packed bf16x2 -> 32 VGPRs; unpack is
//   one shift/and per element. Epilogue re-reads f32 x (L3-resident) so
//   packing error only perturbs a,b (~1e-4 rel -> ~1e-6 abs on y).
//
// Reductions: rows via width-32 shuffle butterfly (no LDS, no barrier);
// columns via one LDS partials round + 256-thread finisher. 2 barriers/iter.
// All LDS patterns XOR-swizzled, verified conflict-free (r1/r2/r5: 0 conflicts).

#define SK_ITERS 15

__device__ __forceinline__ float guarded_rcp(float s) {
    // tf.divide_no_nan semantics for 1/s
    return (s == 0.f) ? 0.f : __builtin_amdgcn_rcpf(s);
}

__device__ __forceinline__ unsigned bf16rn(float f) {   // round-to-nearest-even bf16
    unsigned b = __float_as_uint(f);
    return (b + 0x7fffu + ((b >> 16) & 1u)) >> 16;
}
__device__ __forceinline__ float up_lo(unsigned p) { return __uint_as_float(p << 16); }
__device__ __forceinline__ float up_hi(unsigned p) { return __uint_as_float(p & 0xffff0000u); }

__global__ __launch_bounds__(1024)
void sinkhorn_kernel(const float* __restrict__ xg, float* __restrict__ outg) {
    const int tid  = threadIdx.x;
    const int tr   = tid >> 5;        // row band: rows 8tr..8tr+7
    const int tc   = tid & 31;        // col band: cols 8tc..8tc+7
    const int key  = tc >> 2;         // XOR swizzle key
    const int wv   = tid >> 6;        // wave id 0..15
    const int half = (tid >> 5) & 1;  // half of the wave

    const float* __restrict__ xb = xg   + (size_t)blockIdx.x * 65536;
    float*       __restrict__ ob = outg + (size_t)blockIdx.x * 65536;

    __shared__ float partA[16][256];  // 16 KB column partials (swizzled)
    __shared__ float brcp[256];       //  1 KB per-column 1/colsum (swizzled)

    // ---- load 8x8 f32 tile, pack to bf16x2 (32 persistent VGPRs) ----
    unsigned xp[8][4];                // xp[i][q] = cols (8tc+2q, 8tc+2q+1), row 8tr+i
#pragma unroll
    for (int i = 0; i < 8; ++i) {
        const float4* p = (const float4*)(xb + (tr * 8 + i) * 256 + tc * 8);
        float4 u = p[0], w = p[1];
        xp[i][0] = bf16rn(u.x) | (bf16rn(u.y) << 16);
        xp[i][1] = bf16rn(u.z) | (bf16rn(u.w) << 16);
        xp[i][2] = bf16rn(w.x) | (bf16rn(w.y) << 16);
        xp[i][3] = bf16rn(w.z) | (bf16rn(w.w) << 16);
    }

    // finisher column index (tid < 256): same s2 swizzle the writers use
    const int fcol = (tid & ~7) | ((tid & 7) ^ ((tid >> 5) & 7));

    // ---- peeled col phase for iter 0 (a == 1) ----
    {
        float p[8];
#pragma unroll
        for (int j = 0; j < 8; ++j) p[j] = 0.f;
#pragma unroll
        for (int i = 0; i < 8; ++i)
#pragma unroll
            for (int q = 0; q < 4; ++q) {
                p[2 * q]     += up_lo(xp[i][q]);
                p[2 * q + 1] += up_hi(xp[i][q]);
            }
#pragma unroll
        for (int j = 0; j < 8; ++j) p[j] += __shfl_xor(p[j], 32, 64);
#pragma unroll
        for (int q = 0; q < 4; ++q) {
            const int j = half * 4 + q;
            partA[wv][tc * 8 + (j ^ key)] = p[j];
        }
    }

    float b[8];
    float a[8];

#pragma unroll 1
    for (int it = 0; it < SK_ITERS; ++it) {
        __syncthreads();                                   // BAR_A
        // ---- finisher: 16 partials -> 1/colsum ----
        if (tid < 256) {
            float s0 = (partA[0][fcol] + partA[1][fcol]) + (partA[2][fcol] + partA[3][fcol]);
            float s1 = (partA[4][fcol] + partA[5][fcol]) + (partA[6][fcol] + partA[7][fcol]);
            float s2 = (partA[8][fcol] + partA[9][fcol]) + (partA[10][fcol] + partA[11][fcol]);
            float s3 = (partA[12][fcol] + partA[13][fcol]) + (partA[14][fcol] + partA[15][fcol]);
            brcp[fcol] = guarded_rcp((s0 + s1) + (s2 + s3));
        }
        __syncthreads();                                   // BAR_B

        // ---- row phase: rs_i = sum_j x_ij * b_j ----
#pragma unroll
        for (int j = 0; j < 8; ++j) b[j] = brcp[tc * 8 + (j ^ key)];

        float rs[8];
#pragma unroll
        for (int i = 0; i < 8; ++i) {
            float s = 0.f;
#pragma unroll
            for (int q = 0; q < 4; ++q) {
                s = fmaf(up_lo(xp[i][q]), b[2 * q], s);
                s = fmaf(up_hi(xp[i][q]), b[2 * q + 1], s);
            }
            rs[i] = s;
        }
        // width-32 butterfly (stays within this row band's half-wave)
#pragma unroll
        for (int m = 16; m >= 1; m >>= 1)
#pragma unroll
            for (int i = 0; i < 8; ++i) rs[i] += __shfl_xor(rs[i], m, 64);
#pragma unroll
        for (int i = 0; i < 8; ++i) a[i] = guarded_rcp(rs[i]);

        // ---- col phase for next iter: p_j = sum_i a_i * x_ij ----
        if (it < SK_ITERS - 1) {
            float p[8];
#pragma unroll
            for (int j = 0; j < 8; ++j) p[j] = 0.f;
#pragma unroll
            for (int i = 0; i < 8; ++i)
#pragma unroll
                for (int q = 0; q < 4; ++q) {
                    p[2 * q]     = fmaf(a[i], up_lo(xp[i][q]), p[2 * q]);
                    p[2 * q + 1] = fmaf(a[i], up_hi(xp[i][q]), p[2 * q + 1]);
                }
#pragma unroll
            for (int j = 0; j < 8; ++j) p[j] += __shfl_xor(p[j], 32, 64);
#pragma unroll
            for (int q = 0; q < 4; ++q) {
                const int j = half * 4 + q;
                partA[wv][tc * 8 + (j ^ key)] = p[j];
            }
        }
    }

    // ---- epilogue: y_ij = a_i * x_ij * b_j with f32 x re-read (L3-resident) ----
#pragma unroll
    for (int i = 0; i < 8; ++i) {
        const float ai = a[i];
        const float4* p = (const float4*)(xb + (tr * 8 + i) * 256 + tc * 8);
        float4 u = p[0], w = p[1];
        float4 ou, ow;
        ou.x = ai * u.x * b[0]; ou.y = ai * u.y * b[1];
        ou.z = ai * u.z * b[2]; ou.w = ai * u.w * b[3];
        ow.x = ai * w.x * b[4]; ow.y = ai * w.y * b[5];
        ow.z = ai * w.z * b[6]; ow.w = ai * w.w * b[7];
        float4* po = (float4*)(ob + (tr * 8 + i) * 256 + tc * 8);
        po[0] = ou;
        po[1] = ow;
    }
}

extern "C" void kernel_launch(void* const* d_in, const int* in_sizes, int n_in,
                              void* d_out, int out_size, void* d_ws, size_t ws_size,
                              hipStream_t stream) {
    const float* x = (const float*)d_in[0];
    float* out = (float*)d_out;
    const int batches = in_sizes[0] / 65536;   // 128 for the given shape
    hipLaunchKernelGGL(sinkhorn_kernel, dim3(batches), dim3(1024), 0, stream,
                       x, out);
}

// Round 7
// 197.018 us; speedup vs baseline: 1.3122x; 1.3122x over previous
//
#include <hip/hip_runtime.h>

// Sinkhorn, 128 x (256x256) f32, 15 fixed iterations — matrix-scaling form.
//   b' = 1/(X^T a),  a' = 1/(X b');  y = diag(a) X diag(b) applied once at end.
//
// THE register story (r1..r6 post-mortems):
//   hipcc's AMDGPU backend sets its regalloc occupancy target from STATIC LDS
//   size: at <40 KB LDS it assumes 4+ workgroups/CU -> clamps to 32 waves/CU
//   -> 8 waves/EU -> 64-VGPR budget -> the 64-float persistent tile spills
//   (r2/r4/r5/r6: +24..66 MB scratch traffic, 2-3x slowdown). launch_bounds /
//   waves_per_eu hints do NOT override it.
//   FIX: pad LDS past 80 KB (partA row stride 256 -> 1536, genuinely used so
//   it can't be DCE'd). Backend then targets 1 wg/CU = 4 waves/EU = 128 VGPRs.
//   Cost: none — grid is 128 blocks on 256 CUs, so >1 block/CU never happens.
//   Stride 1536 ≡ 0 (mod 32) keeps every verified bank pattern identical.
//
// Reductions: rows via width-32 shuffle butterfly (no LDS, no barrier);
// columns via 16 wave-partials in LDS + 256-thread finisher. 2 barriers/iter.
// All LDS patterns XOR-swizzled; measured 0 bank conflicts in r1/r2/r5/r6.

#define SK_ITERS 15
#define PSTRIDE 1536   // partA row stride in floats (pads LDS to ~97 KB)

__device__ __forceinline__ float guarded_rcp(float s) {
    // tf.divide_no_nan semantics for 1/s
    return (s == 0.f) ? 0.f : __builtin_amdgcn_rcpf(s);
}

__global__ __launch_bounds__(1024)
void sinkhorn_kernel(const float* __restrict__ xg, float* __restrict__ outg) {
    const int tid  = threadIdx.x;
    const int tr   = tid >> 5;        // row band (rows 8tr..8tr+7)
    const int tc   = tid & 31;        // col band (cols 8tc..8tc+7)
    const int key  = tc >> 2;         // XOR swizzle key 0..7
    const int wv   = tid >> 6;        // wave id 0..15
    const int half = (tid >> 5) & 1;  // which 32-lane half of the wave

    const float* __restrict__ xb = xg   + (size_t)blockIdx.x * 65536;
    float*       __restrict__ ob = outg + (size_t)blockIdx.x * 65536;

    __shared__ float partA[16][PSTRIDE];  // 96 KB (only [0..255] of each row used)
    __shared__ float brcp[256];           //  1 KB per-column 1/colsum (swizzled)

    // ---- load 8x8 tile into registers; read-only for all 15 iters ----
    float x[8][8];
#pragma unroll
    for (int i = 0; i < 8; ++i) {
        const float4* p = (const float4*)(xb + (tr * 8 + i) * 256 + tc * 8);
        float4 u = p[0], w = p[1];
        x[i][0] = u.x; x[i][1] = u.y; x[i][2] = u.z; x[i][3] = u.w;
        x[i][4] = w.x; x[i][5] = w.y; x[i][6] = w.z; x[i][7] = w.w;
    }

    float a[8];
#pragma unroll
    for (int i = 0; i < 8; ++i) a[i] = 1.f;   // scaling starts at identity
    float b[8];

    // finisher's swizzled column index (tid < 256), matches the writers:
    // c -> (c&~7) | ((c&7) ^ ((c>>5)&7))
    const int fidx = (tid & ~7) | ((tid & 7) ^ ((tid >> 5) & 7));

#pragma unroll 1
    for (int it = 0; it < SK_ITERS; ++it) {
        // ======== column phase: p_j = sum_i a_i * x_ij ========
        float p[8];
#pragma unroll
        for (int j = 0; j < 8; ++j) {
            float s = a[0] * x[0][j];
#pragma unroll
            for (int i = 1; i < 8; ++i) s = fmaf(a[i], x[i][j], s);
            p[j] = s;
        }
        // combine the two row-bands sharing this wave: 32 -> 16 partials/col
#pragma unroll
        for (int j = 0; j < 8; ++j) p[j] += __shfl_xor(p[j], 32, 64);
        // both halves hold identical p[0..7]; split the 8 writes 4/4.
        // Banks across lanes: 8*(tc&3) + (j^key) -> all 32 distinct = free.
        {
            const int j0 = half * 4;
#pragma unroll
            for (int q = 0; q < 4; ++q) {
                const int j = j0 + q;
                partA[wv][tc * 8 + (j ^ key)] = p[j];
            }
        }
        __syncthreads();

        // ---- finisher: waves 0-3 (one per SIMD) reduce 16 partials + rcp ----
        if (tid < 256) {
            float s0 = (partA[0][fidx] + partA[1][fidx]) + (partA[2][fidx] + partA[3][fidx]);
            float s1 = (partA[4][fidx] + partA[5][fidx]) + (partA[6][fidx] + partA[7][fidx]);
            float s2 = (partA[8][fidx] + partA[9][fidx]) + (partA[10][fidx] + partA[11][fidx]);
            float s3 = (partA[12][fidx] + partA[13][fidx]) + (partA[14][fidx] + partA[15][fidx]);
            brcp[fidx] = guarded_rcp((s0 + s1) + (s2 + s3));
        }
        __syncthreads();

        // ======== row phase: rs_i = sum_j x_ij * b'_j ========
#pragma unroll
        for (int j = 0; j < 8; ++j) b[j] = brcp[tc * 8 + (j ^ key)];

        float rs[8];
#pragma unroll
        for (int i = 0; i < 8; ++i) {
            float s = x[i][0] * b[0];
#pragma unroll
            for (int j = 1; j < 8; ++j) s = fmaf(x[i][j], b[j], s);
            rs[i] = s;
        }
        // width-32 butterfly within this row band's half-wave
#pragma unroll
        for (int m = 16; m >= 1; m >>= 1) {
#pragma unroll
            for (int i = 0; i < 8; ++i) rs[i] += __shfl_xor(rs[i], m, 64);
        }
#pragma unroll
        for (int i = 0; i < 8; ++i) a[i] = guarded_rcp(rs[i]);
        // No extra barrier: next iter's partA writes are post-barrier-2;
        // finisher's partA reads were pre-barrier-2; brcp reads above finish
        // before this thread reaches next iter's barrier-1.
    }

    // ---- epilogue: y_ij = a_i * x_ij * b_j, coalesced float4 stores ----
#pragma unroll
    for (int i = 0; i < 8; ++i) {
        const float ai = a[i];
        float4 u, w;
        u.x = ai * x[i][0] * b[0]; u.y = ai * x[i][1] * b[1];
        u.z = ai * x[i][2] * b[2]; u.w = ai * x[i][3] * b[3];
        w.x = ai * x[i][4] * b[4]; w.y = ai * x[i][5] * b[5];
        w.z = ai * x[i][6] * b[6]; w.w = ai * x[i][7] * b[7];
        float4* po = (float4*)(ob + (tr * 8 + i) * 256 + tc * 8);
        po[0] = u;
        po[1] = w;
    }
}

extern "C" void kernel_launch(void* const* d_in, const int* in_sizes, int n_in,
                              void* d_out, int out_size, void* d_ws, size_t ws_size,
                              hipStream_t stream) {
    const float* x = (const float*)d_in[0];
    float* out = (float*)d_out;
    const int batches = in_sizes[0] / 65536;   // 128 for the given shape
    hipLaunchKernelGGL(sinkhorn_kernel, dim3(batches), dim3(1024), 0, stream,
                       x, out);
}